// Round 1
// baseline (363.839 us; speedup 1.0000x reference)
//
#include <hip/hip_runtime.h>
#include <hip/hip_bf16.h>

#define ENC_DIM 2048
#define DEC_DIM 512
#define ATT_DIM 512
#define BATCH   256
#define NPIX    196

typedef __attribute__((ext_vector_type(8)))  short short8;
typedef __attribute__((ext_vector_type(16))) float f32x16;

__device__ __forceinline__ short f2bf(float x) {
    // round-to-nearest-even bf16 (inputs are finite normals; no NaN path needed)
    unsigned u = __builtin_bit_cast(unsigned, x);
    unsigned r = (u + 0x7FFFu + ((u >> 16) & 1u)) >> 16;
    return (short)r;
}

// ---------------------------------------------------------------------------
// prep: blocks [0,256)   -> att2pb[b][a] = b_enc[a] + b_dec[a] + h[b]·W_dec[:,a]
//       blocks [256,768) -> pack W_enc (fp32, [K=2048][N=512]) into bf16 MFMA
//                           fragment order for 32x32x16:
//                           Wpack[nt][kb16][lane][j] ,
//                           element = W_enc[kb16*16 + (lane>>5)*8 + j][nt*32 + (lane&31)]
// ---------------------------------------------------------------------------
__global__ __launch_bounds__(256) void bahdanau_prep(
    const float* __restrict__ dec_h, const float* __restrict__ W_enc,
    const float* __restrict__ b_enc, const float* __restrict__ W_dec,
    const float* __restrict__ b_dec,
    float* __restrict__ att2pb, short* __restrict__ Wpack)
{
    int blk = blockIdx.x;
    if (blk < BATCH) {
        __shared__ float hs[DEC_DIM];
        int b = blk;
        for (int i = threadIdx.x; i < DEC_DIM; i += 256) hs[i] = dec_h[b * DEC_DIM + i];
        __syncthreads();
        for (int a = threadIdx.x; a < ATT_DIM; a += 256) {
            float s = 0.f;
            #pragma unroll 8
            for (int d = 0; d < DEC_DIM; ++d) s += hs[d] * W_dec[d * ATT_DIM + a];
            att2pb[b * ATT_DIM + a] = s + b_dec[a] + b_enc[a];
        }
    } else {
        int c    = (blk - BATCH) * 256 + threadIdx.x;   // 0 .. 131071 (16*128*64)
        int lane = c & 63;
        int kb16 = (c >> 6) & 127;
        int nt   = c >> 13;
        int n     = nt * 32 + (lane & 31);
        int kbase = kb16 * 16 + (lane >> 5) * 8;
        short8 v;
        #pragma unroll
        for (int j = 0; j < 8; ++j) v[j] = f2bf(W_enc[(kbase + j) * ATT_DIM + n]);
        *reinterpret_cast<short8*>(Wpack + (size_t)c * 8) = v;
    }
}

// ---------------------------------------------------------------------------
// main: one block per b. 8 waves; wave w owns rows [w*32, w*32+32) (rows >=196
// are clamped to row 195 -> no extra HBM, scores for pads ignored).
// N=512 in two chunks of 256 (8 n-tiles of 32). K streamed in blocks of 64
// (4 MFMA k-steps), staged LDS in fragment order (linear ds_read_b128).
// Then relu(acc + att2pb)·w_full -> row scores -> softmax -> context.
// ---------------------------------------------------------------------------
__global__ __launch_bounds__(512) void bahdanau_main(
    const float* __restrict__ enc, const float* __restrict__ w_full,
    const float* __restrict__ att2pb, const short* __restrict__ Wpack,
    float* __restrict__ out_ctx, float* __restrict__ out_alpha)
{
    __shared__ __align__(16) short Bs[8 * 4 * 64 * 8];  // 32 KiB: [nt][kb16][lane][8]
    __shared__ float red[264];                           // scores/alpha + m,sum

    const int b    = blockIdx.x;
    const int tid  = threadIdx.x;
    const int lane = tid & 63;
    const int wid  = tid >> 6;

    const float* encB = enc + (size_t)b * NPIX * ENC_DIM;

    const int arow  = wid * 32 + (lane & 31);
    const int arowc = arow < NPIX ? arow : NPIX - 1;
    const float* aptr = encB + (size_t)arowc * ENC_DIM + (lane >> 5) * 8;

    float sp[16];
    #pragma unroll
    for (int r = 0; r < 16; ++r) sp[r] = 0.f;

    for (int nc = 0; nc < 2; ++nc) {
        f32x16 acc[8];
        #pragma unroll
        for (int t = 0; t < 8; ++t)
            #pragma unroll
            for (int r = 0; r < 16; ++r) acc[t][r] = 0.f;

        for (int kb = 0; kb < ENC_DIM / 64; ++kb) {
            __syncthreads();
            {   // stage 32 KiB of packed W into LDS (linear copy, coalesced)
                const short8* src = reinterpret_cast<const short8*>(Wpack);
                short8*       dst = reinterpret_cast<short8*>(Bs);
                #pragma unroll
                for (int i = 0; i < 4; ++i) {
                    int idx = tid + i * 512;          // 0..2047 16B-chunks
                    int c   = idx >> 6;               // 0..31
                    int ln  = idx & 63;
                    int nt   = nc * 8 + (c >> 2);
                    int kb16 = kb * 4 + (c & 3);
                    dst[idx] = src[(nt * 128 + kb16) * 64 + ln];
                }
            }
            __syncthreads();
            #pragma unroll
            for (int kk = 0; kk < 4; ++kk) {
                const float* ap = aptr + kb * 64 + kk * 16;
                float4 f0 = *reinterpret_cast<const float4*>(ap);
                float4 f1 = *reinterpret_cast<const float4*>(ap + 4);
                short8 afr;
                afr[0] = f2bf(f0.x); afr[1] = f2bf(f0.y);
                afr[2] = f2bf(f0.z); afr[3] = f2bf(f0.w);
                afr[4] = f2bf(f1.x); afr[5] = f2bf(f1.y);
                afr[6] = f2bf(f1.z); afr[7] = f2bf(f1.w);
                #pragma unroll
                for (int t = 0; t < 8; ++t) {
                    short8 bfr = *reinterpret_cast<const short8*>(
                        Bs + ((t * 4 + kk) * 64 + lane) * 8);
                    acc[t] = __builtin_amdgcn_mfma_f32_32x32x16_bf16(afr, bfr, acc[t], 0, 0, 0);
                }
            }
        }
        // fold this n-chunk into per-row score partials: relu(acc + c2) * w_full
        #pragma unroll
        for (int t = 0; t < 8; ++t) {
            int col  = nc * 256 + t * 32 + (lane & 31);
            float c2 = att2pb[b * ATT_DIM + col];
            float wf = w_full[col];
            #pragma unroll
            for (int r = 0; r < 16; ++r) {
                float v = acc[t][r] + c2;
                v = v > 0.f ? v : 0.f;
                sp[r] += v * wf;
            }
        }
    }

    // reduce row partials across the 32 lanes holding the same row
    #pragma unroll
    for (int r = 0; r < 16; ++r) {
        float v = sp[r];
        v += __shfl_xor(v, 1);
        v += __shfl_xor(v, 2);
        v += __shfl_xor(v, 4);
        v += __shfl_xor(v, 8);
        v += __shfl_xor(v, 16);
        sp[r] = v;
    }
    if ((lane & 31) == 0) {
        #pragma unroll
        for (int r = 0; r < 16; ++r) {
            int p = wid * 32 + (r & 3) + 8 * (r >> 2) + 4 * (lane >> 5);
            red[p] = sp[r];
        }
    }
    __syncthreads();

    // softmax over 196 scores (wave 0); b_full is softmax-invariant -> dropped
    if (wid == 0) {
        float s0 = red[lane], s1 = red[lane + 64], s2 = red[lane + 128];
        float s3 = (lane < NPIX - 192) ? red[lane + 192] : -3.4e38f;
        float m = fmaxf(fmaxf(s0, s1), fmaxf(s2, s3));
        #pragma unroll
        for (int d = 1; d <= 32; d <<= 1) m = fmaxf(m, __shfl_xor(m, d));
        float e = __expf(s0 - m) + __expf(s1 - m) + __expf(s2 - m)
                + ((lane < NPIX - 192) ? __expf(s3 - m) : 0.f);
        #pragma unroll
        for (int d = 1; d <= 32; d <<= 1) e += __shfl_xor(e, d);
        if (lane == 0) { red[256] = m; red[257] = e; }
    }
    __syncthreads();
    float m    = red[256];
    float rinv = 1.f / red[257];
    if (tid < NPIX) {
        float a = __expf(red[tid] - m) * rinv;
        red[tid] = a;
        out_alpha[b * NPIX + tid] = a;
    }
    __syncthreads();

    // context[b, :] = sum_p alpha[p] * enc[b, p, :]   (thread -> one float4 col)
    float4 ctx = {0.f, 0.f, 0.f, 0.f};
    const float4* enc4 = reinterpret_cast<const float4*>(encB);
    for (int p = 0; p < NPIX; ++p) {
        float a  = red[p];
        float4 v = enc4[p * (ENC_DIM / 4) + tid];
        ctx.x += a * v.x; ctx.y += a * v.y; ctx.z += a * v.z; ctx.w += a * v.w;
    }
    reinterpret_cast<float4*>(out_ctx)[(size_t)b * (ENC_DIM / 4) + tid] = ctx;
}

extern "C" void kernel_launch(void* const* d_in, const int* in_sizes, int n_in,
                              void* d_out, int out_size, void* d_ws, size_t ws_size,
                              hipStream_t stream) {
    const float* enc    = (const float*)d_in[0];
    const float* dech   = (const float*)d_in[1];
    const float* W_enc  = (const float*)d_in[2];
    const float* b_enc  = (const float*)d_in[3];
    const float* W_dec  = (const float*)d_in[4];
    const float* b_dec  = (const float*)d_in[5];
    const float* w_full = (const float*)d_in[6];
    // d_in[7] = b_full: softmax-invariant, unused.

    float* att2pb = (float*)d_ws;                          // 256*512*4   = 512 KiB
    short* Wpack  = (short*)((char*)d_ws + 512 * 1024);    // 2048*512*2  = 2 MiB

    float* out_ctx   = (float*)d_out;
    float* out_alpha = out_ctx + (size_t)BATCH * ENC_DIM;

    bahdanau_prep<<<768, 256, 0, stream>>>(dech, W_enc, b_enc, W_dec, b_dec, att2pb, Wpack);
    bahdanau_main<<<BATCH, 512, 0, stream>>>(enc, w_full, att2pb, Wpack, out_ctx, out_alpha);
}